// Round 1
// baseline (138.769 us; speedup 1.0000x reference)
//
#include <hip/hip_runtime.h>
#include <hip/hip_bf16.h>

#define IN_F 256
#define OUT_F 128
#define GEMM_ROWS 8      // rows per block in GEMM
#define SPMM_ROWS 8      // rows per block in SpMM

// -------- Kernel 1: H = X @ W   (X: [n,256] f32, W: [256,128] f32) --------
__global__ __launch_bounds__(128)
void gemm_xw_kernel(const float* __restrict__ X, const float* __restrict__ W,
                    float* __restrict__ H, int n)
{
    __shared__ float xs[GEMM_ROWS][IN_F];   // 8 KB
    const int r0 = blockIdx.x * GEMM_ROWS;
    const int c  = threadIdx.x;             // 0..127 output column

    // cooperative load of the 8x256 X tile (rows are contiguous)
    {
        const float4* Xv  = (const float4*)(X + (size_t)r0 * IN_F);
        float4*       xsv = (float4*)&xs[0][0];
        const int nvec = GEMM_ROWS * IN_F / 4;   // 512
        for (int i = threadIdx.x; i < nvec; i += 128) {
            int row = r0 + (i * 4) / IN_F;
            if (row < n) xsv[i] = Xv[i];
            else         xsv[i] = make_float4(0.f, 0.f, 0.f, 0.f);
        }
    }
    __syncthreads();

    float acc[GEMM_ROWS];
    #pragma unroll
    for (int r = 0; r < GEMM_ROWS; ++r) acc[r] = 0.f;

    #pragma unroll 4
    for (int k = 0; k < IN_F; ++k) {
        const float w = W[k * OUT_F + c];       // coalesced across lanes
        #pragma unroll
        for (int r = 0; r < GEMM_ROWS; ++r)
            acc[r] = fmaf(xs[r][k], w, acc[r]); // xs broadcast: conflict-free
    }

    #pragma unroll
    for (int r = 0; r < GEMM_ROWS; ++r) {
        const int row = r0 + r;
        if (row < n) H[(size_t)row * OUT_F + c] = acc[r];
    }
}

// -------- Kernel 2: out = relu(A @ H + bias)   (CSR, f32) --------
__global__ __launch_bounds__(256)
void spmm_bias_relu_kernel(const int* __restrict__ row_ptr,
                           const int* __restrict__ col_idx,
                           const float* __restrict__ val,
                           const float* __restrict__ H,
                           const float* __restrict__ bias,
                           float* __restrict__ out, int n)
{
    const int row = blockIdx.x * SPMM_ROWS + (threadIdx.x >> 5); // 32 lanes/row
    const int c4  = threadIdx.x & 31;                            // float4 idx 0..31
    if (row >= n) return;

    const int start = row_ptr[row];
    const int end   = row_ptr[row + 1];

    float4 acc = make_float4(0.f, 0.f, 0.f, 0.f);
    for (int e = start; e < end; ++e) {
        const int   col = col_idx[e];
        const float v   = val[e];
        const float4 hv = ((const float4*)(H + (size_t)col * OUT_F))[c4];
        acc.x = fmaf(v, hv.x, acc.x);
        acc.y = fmaf(v, hv.y, acc.y);
        acc.z = fmaf(v, hv.z, acc.z);
        acc.w = fmaf(v, hv.w, acc.w);
    }

    const float4 b = ((const float4*)bias)[c4];
    acc.x = fmaxf(acc.x + b.x, 0.f);
    acc.y = fmaxf(acc.y + b.y, 0.f);
    acc.z = fmaxf(acc.z + b.z, 0.f);
    acc.w = fmaxf(acc.w + b.w, 0.f);

    ((float4*)(out + (size_t)row * OUT_F))[c4] = acc;
}

extern "C" void kernel_launch(void* const* d_in, const int* in_sizes, int n_in,
                              void* d_out, int out_size, void* d_ws, size_t ws_size,
                              hipStream_t stream)
{
    // input order per setup_inputs():
    // 0 nnz, 1 row_ptr_s, 2 col_idx_s, 3 edge_val_csr_s, 4 p_csr, 5 q_csr,
    // 6 col_ptr_s, 7 row_idx_s, 8 edge_val_csc_s, 9 p_csc, 10 q_csc,
    // 11 in_feat, 12 W, 13 bias
    const int*   row_ptr = (const int*)  d_in[1];
    const int*   col_idx = (const int*)  d_in[2];
    const float* edgeval = (const float*)d_in[3];
    const float* in_feat = (const float*)d_in[11];
    const float* W       = (const float*)d_in[12];
    const float* bias    = (const float*)d_in[13];

    const int n = in_sizes[11] / IN_F;   // 50000 nodes

    float* H = (float*)d_ws;             // [n, OUT_F] f32 scratch (25.6 MB)

    const int gemm_blocks = (n + GEMM_ROWS - 1) / GEMM_ROWS;
    gemm_xw_kernel<<<gemm_blocks, 128, 0, stream>>>(in_feat, W, H, n);

    const int spmm_blocks = (n + SPMM_ROWS - 1) / SPMM_ROWS;
    spmm_bias_relu_kernel<<<spmm_blocks, 256, 0, stream>>>(
        row_ptr, col_idx, edgeval, H, bias, (float*)d_out, n);
}

// Round 2
// 69.122 us; speedup vs baseline: 2.0076x; 2.0076x over previous
//
#include <hip/hip_runtime.h>
#include <hip/hip_bf16.h>

#define IN_F 256
#define OUT_F 128
#define BM 32                 // GEMM rows per block
#define GEMM_THREADS 512      // 8 waves: 2 (M) x 4 (N)

typedef __bf16 bf16x8 __attribute__((ext_vector_type(8)));
typedef float  f32x4  __attribute__((ext_vector_type(4)));

// -------- Kernel 0: Wt[n][k] = bf16(W[k][n])  (128x256 bf16, 64 KB) --------
__global__ __launch_bounds__(128)
void wprep_kernel(const float* __restrict__ W, __bf16* __restrict__ Wt)
{
    const int k = blockIdx.x;      // 0..255
    const int nn = threadIdx.x;    // 0..127
    Wt[nn * IN_F + k] = (__bf16)W[k * OUT_F + nn];
}

// -------- Kernel 1: H = bf16(X @ W)  via MFMA 16x16x32 --------
__global__ __launch_bounds__(GEMM_THREADS)
void gemm_xw_kernel(const float* __restrict__ X, const __bf16* __restrict__ Wt,
                    __bf16* __restrict__ H, int n)
{
    __shared__ __bf16 xs[BM * IN_F];   // 16 KB, XOR-swizzled

    const int tid  = threadIdx.x;
    const int lane = tid & 63;
    const int wid  = tid >> 6;         // 0..7
    const int wm   = wid >> 2;         // 0..1 (16-row band)
    const int wn   = wid & 3;          // 0..3 (32-col band)
    const int r0   = blockIdx.x * BM;

    // ---- load B fragments once (Wt is L2-resident) ----
    // frag layout: n = lane&15, k = (lane>>4)*8 + j
    bf16x8 bfrag[8][2];
    {
        const int nbase = wn * 32 + (lane & 15);
        const int kbase = (lane >> 4) * 8;
        #pragma unroll
        for (int kk = 0; kk < 8; ++kk) {
            #pragma unroll
            for (int nf = 0; nf < 2; ++nf) {
                const __bf16* p = Wt + (size_t)(nbase + nf * 16) * IN_F + kk * 32 + kbase;
                bfrag[kk][nf] = *(const bf16x8*)p;
            }
        }
    }

    // ---- stage X tile (32 x 256) f32 -> bf16 LDS, swizzled ----
    // chunk c -> row = c>>5, k = (c&31)*8 ; 1024 chunks, 2 per thread
    #pragma unroll
    for (int i = 0; i < 2; ++i) {
        const int c   = tid + i * GEMM_THREADS;
        const int row = c >> 5;
        const int k   = (c & 31) * 8;
        const int gr  = r0 + row;
        bf16x8 v;
        if (gr < n) {
            const float4 a = *(const float4*)(X + (size_t)gr * IN_F + k);
            const float4 b = *(const float4*)(X + (size_t)gr * IN_F + k + 4);
            v[0] = (__bf16)a.x; v[1] = (__bf16)a.y; v[2] = (__bf16)a.z; v[3] = (__bf16)a.w;
            v[4] = (__bf16)b.x; v[5] = (__bf16)b.y; v[6] = (__bf16)b.z; v[7] = (__bf16)b.w;
        } else {
            #pragma unroll
            for (int j = 0; j < 8; ++j) v[j] = (__bf16)0.f;
        }
        const int sidx = (row * IN_F + k) ^ ((row & 7) << 3);
        *(bf16x8*)&xs[sidx] = v;
    }
    __syncthreads();

    // ---- MFMA main: each wave 16 rows x 32 cols ----
    f32x4 acc[2];
    acc[0] = (f32x4)0.f; acc[1] = (f32x4)0.f;

    const int arow  = wm * 16 + (lane & 15);
    const int akoff = (lane >> 4) * 8;
    #pragma unroll
    for (int kk = 0; kk < 8; ++kk) {
        const int sidx = (arow * IN_F + kk * 32 + akoff) ^ ((arow & 7) << 3);
        const bf16x8 a = *(const bf16x8*)&xs[sidx];
        acc[0] = __builtin_amdgcn_mfma_f32_16x16x32_bf16(a, bfrag[kk][0], acc[0], 0, 0, 0);
        acc[1] = __builtin_amdgcn_mfma_f32_16x16x32_bf16(a, bfrag[kk][1], acc[1], 0, 0, 0);
    }

    // ---- store H (bf16): C/D layout col=lane&15, row=(lane>>4)*4+j ----
    const int crow0 = r0 + wm * 16 + (lane >> 4) * 4;
    const int ccol0 = wn * 32 + (lane & 15);
    #pragma unroll
    for (int nf = 0; nf < 2; ++nf) {
        #pragma unroll
        for (int j = 0; j < 4; ++j) {
            const int row = crow0 + j;
            if (row < n)
                H[(size_t)row * OUT_F + ccol0 + nf * 16] = (__bf16)acc[nf][j];
        }
    }
}

// -------- Kernel 2: out = relu(A @ H + bias)  (CSR, H bf16, acc f32) --------
__global__ __launch_bounds__(256)
void spmm_bias_relu_kernel(const int* __restrict__ row_ptr,
                           const int* __restrict__ col_idx,
                           const float* __restrict__ val,
                           const __bf16* __restrict__ H,
                           const float* __restrict__ bias,
                           float* __restrict__ out, int n)
{
    const int row  = blockIdx.x * 16 + (threadIdx.x >> 4);  // 16 lanes/row
    const int lid  = threadIdx.x & 63;
    const int gb   = lid & 48;            // group base within wave
    const int c8   = (threadIdx.x & 15) * 8;
    if (row >= n) return;

    const int s = row_ptr[row];
    const int e = row_ptr[row + 1];

    float acc[8];
    #pragma unroll
    for (int j = 0; j < 8; ++j) acc[j] = 0.f;

    for (int base = s; base < e; base += 16) {
        const int ee   = base + (lid & 15);
        const int colv = (ee < e) ? col_idx[ee] : 0;
        const float vv = (ee < e) ? val[ee] : 0.f;
        const int m = min(16, e - base);
        for (int i = 0; i < m; ++i) {
            const int   col = __shfl(colv, gb + i);
            const float v   = __shfl(vv, gb + i);
            const bf16x8 hv = *(const bf16x8*)(H + (size_t)col * OUT_F + c8);
            #pragma unroll
            for (int j = 0; j < 8; ++j)
                acc[j] = fmaf(v, (float)hv[j], acc[j]);
        }
    }

    #pragma unroll
    for (int j = 0; j < 8; ++j) {
        acc[j] += bias[c8 + j];
        acc[j] = fmaxf(acc[j], 0.f);
    }
    float4 o0 = make_float4(acc[0], acc[1], acc[2], acc[3]);
    float4 o1 = make_float4(acc[4], acc[5], acc[6], acc[7]);
    *(float4*)(out + (size_t)row * OUT_F + c8)     = o0;
    *(float4*)(out + (size_t)row * OUT_F + c8 + 4) = o1;
}

extern "C" void kernel_launch(void* const* d_in, const int* in_sizes, int n_in,
                              void* d_out, int out_size, void* d_ws, size_t ws_size,
                              hipStream_t stream)
{
    // inputs: 0 nnz, 1 row_ptr, 2 col_idx, 3 edge_val_csr, 4 p, 5 q,
    //         6 col_ptr, 7 row_idx, 8 edge_val_csc, 9 p, 10 q, 11 in_feat, 12 W, 13 bias
    const int*   row_ptr = (const int*)  d_in[1];
    const int*   col_idx = (const int*)  d_in[2];
    const float* edgeval = (const float*)d_in[3];
    const float* in_feat = (const float*)d_in[11];
    const float* W       = (const float*)d_in[12];
    const float* bias    = (const float*)d_in[13];

    const int n = in_sizes[11] / IN_F;   // 50000 nodes

    __bf16* H  = (__bf16*)d_ws;                                  // [n][128] bf16
    __bf16* Wt = (__bf16*)((char*)d_ws + (size_t)n * OUT_F * 2); // [128][256] bf16

    wprep_kernel<<<IN_F, OUT_F, 0, stream>>>(W, Wt);

    const int gemm_blocks = (n + BM - 1) / BM;
    gemm_xw_kernel<<<gemm_blocks, GEMM_THREADS, 0, stream>>>(in_feat, Wt, H, n);

    const int spmm_blocks = (n + 15) / 16;
    spmm_bias_relu_kernel<<<spmm_blocks, 256, 0, stream>>>(
        row_ptr, col_idx, edgeval, H, bias, (float*)d_out, n);
}

// Round 3
// 67.903 us; speedup vs baseline: 2.0436x; 1.0179x over previous
//
#include <hip/hip_runtime.h>
#include <hip/hip_bf16.h>

#define IN_F 256
#define OUT_F 128
#define BM 32                 // GEMM rows per block
#define GEMM_THREADS 512      // 8 waves: 2 (M) x 4 (N)

typedef __bf16 bf16x8 __attribute__((ext_vector_type(8)));
typedef float  f32x4  __attribute__((ext_vector_type(4)));

// -------- Kernel 0: Wt[n][k] = bf16(W[k][n])  (128x256 bf16, 64 KB) --------
__global__ __launch_bounds__(128)
void wprep_kernel(const float* __restrict__ W, __bf16* __restrict__ Wt)
{
    const int k = blockIdx.x;      // 0..255
    const int nn = threadIdx.x;    // 0..127
    Wt[nn * IN_F + k] = (__bf16)W[k * OUT_F + nn];
}

// -------- Kernel 1: H = bf16(X @ W)  via MFMA 16x16x32 --------
__global__ __launch_bounds__(GEMM_THREADS)
void gemm_xw_kernel(const float* __restrict__ X, const __bf16* __restrict__ Wt,
                    __bf16* __restrict__ H, int n)
{
    __shared__ __bf16 xs[BM * IN_F];   // 16 KB, XOR-swizzled

    const int tid  = threadIdx.x;
    const int lane = tid & 63;
    const int wid  = tid >> 6;         // 0..7
    const int wm   = wid >> 2;         // 0..1 (16-row band)
    const int wn   = wid & 3;          // 0..3 (32-col band)
    const int r0   = blockIdx.x * BM;

    // ---- load B fragments once (Wt is L2-resident) ----
    // frag layout: n = lane&15, k = (lane>>4)*8 + j
    bf16x8 bfrag[8][2];
    {
        const int nbase = wn * 32 + (lane & 15);
        const int kbase = (lane >> 4) * 8;
        #pragma unroll
        for (int kk = 0; kk < 8; ++kk) {
            #pragma unroll
            for (int nf = 0; nf < 2; ++nf) {
                const __bf16* p = Wt + (size_t)(nbase + nf * 16) * IN_F + kk * 32 + kbase;
                bfrag[kk][nf] = *(const bf16x8*)p;
            }
        }
    }

    // ---- stage X tile (32 x 256) f32 -> bf16 LDS, swizzled ----
    #pragma unroll
    for (int i = 0; i < 2; ++i) {
        const int c   = tid + i * GEMM_THREADS;
        const int row = c >> 5;
        const int k   = (c & 31) * 8;
        const int gr  = r0 + row;
        bf16x8 v;
        if (gr < n) {
            const float4 a = *(const float4*)(X + (size_t)gr * IN_F + k);
            const float4 b = *(const float4*)(X + (size_t)gr * IN_F + k + 4);
            v[0] = (__bf16)a.x; v[1] = (__bf16)a.y; v[2] = (__bf16)a.z; v[3] = (__bf16)a.w;
            v[4] = (__bf16)b.x; v[5] = (__bf16)b.y; v[6] = (__bf16)b.z; v[7] = (__bf16)b.w;
        } else {
            #pragma unroll
            for (int j = 0; j < 8; ++j) v[j] = (__bf16)0.f;
        }
        const int sidx = (row * IN_F + k) ^ ((row & 7) << 3);
        *(bf16x8*)&xs[sidx] = v;
    }
    __syncthreads();

    // ---- MFMA main: each wave 16 rows x 32 cols ----
    f32x4 acc[2];
    acc[0] = (f32x4)0.f; acc[1] = (f32x4)0.f;

    const int arow  = wm * 16 + (lane & 15);
    const int akoff = (lane >> 4) * 8;
    #pragma unroll
    for (int kk = 0; kk < 8; ++kk) {
        const int sidx = (arow * IN_F + kk * 32 + akoff) ^ ((arow & 7) << 3);
        const bf16x8 a = *(const bf16x8*)&xs[sidx];
        acc[0] = __builtin_amdgcn_mfma_f32_16x16x32_bf16(a, bfrag[kk][0], acc[0], 0, 0, 0);
        acc[1] = __builtin_amdgcn_mfma_f32_16x16x32_bf16(a, bfrag[kk][1], acc[1], 0, 0, 0);
    }

    // ---- store H (bf16): C/D layout col=lane&15, row=(lane>>4)*4+j ----
    const int crow0 = r0 + wm * 16 + (lane >> 4) * 4;
    const int ccol0 = wn * 32 + (lane & 15);
    #pragma unroll
    for (int nf = 0; nf < 2; ++nf) {
        #pragma unroll
        for (int j = 0; j < 4; ++j) {
            const int row = crow0 + j;
            if (row < n)
                H[(size_t)row * OUT_F + ccol0 + nf * 16] = (__bf16)acc[nf][j];
        }
    }
}

// -------- Kernel 2: out = relu(A @ H + bias)  (CSR, H bf16, acc f32) --------
// 16 lanes per row, all 16 gathers in flight (known DEG=16 fast path).
__global__ __launch_bounds__(256)
void spmm_bias_relu_kernel(const int* __restrict__ row_ptr,
                           const int* __restrict__ col_idx,
                           const float* __restrict__ val,
                           const __bf16* __restrict__ H,
                           const float* __restrict__ bias,
                           float* __restrict__ out, int n)
{
    const int row = blockIdx.x * 16 + (threadIdx.x >> 4);
    const int c8  = (threadIdx.x & 15) * 8;
    if (row >= n) return;

    const int s = row_ptr[row];
    const int e = row_ptr[row + 1];

    float acc[8];
    #pragma unroll
    for (int j = 0; j < 8; ++j) acc[j] = 0.f;

    if (e - s == 16 && (s & 3) == 0) {
        // ---- fast path: 16 edges, vector-load metadata, 16 gathers in flight ----
        int4   ci[4];
        float4 vi[4];
        #pragma unroll
        for (int i = 0; i < 4; ++i) {
            ci[i] = ((const int4*)(col_idx + s))[i];
            vi[i] = ((const float4*)(val + s))[i];
        }
        const int cols[16] = { ci[0].x, ci[0].y, ci[0].z, ci[0].w,
                               ci[1].x, ci[1].y, ci[1].z, ci[1].w,
                               ci[2].x, ci[2].y, ci[2].z, ci[2].w,
                               ci[3].x, ci[3].y, ci[3].z, ci[3].w };
        const float vals[16] = { vi[0].x, vi[0].y, vi[0].z, vi[0].w,
                                 vi[1].x, vi[1].y, vi[1].z, vi[1].w,
                                 vi[2].x, vi[2].y, vi[2].z, vi[2].w,
                                 vi[3].x, vi[3].y, vi[3].z, vi[3].w };
        bf16x8 hv[16];
        #pragma unroll
        for (int i = 0; i < 16; ++i)
            hv[i] = *(const bf16x8*)(H + (size_t)cols[i] * OUT_F + c8);
        #pragma unroll
        for (int i = 0; i < 16; ++i) {
            #pragma unroll
            for (int j = 0; j < 8; ++j)
                acc[j] = fmaf(vals[i], (float)hv[i][j], acc[j]);
        }
    } else {
        // ---- general fallback ----
        for (int ee = s; ee < e; ++ee) {
            const int   col = col_idx[ee];
            const float v   = val[ee];
            const bf16x8 hv = *(const bf16x8*)(H + (size_t)col * OUT_F + c8);
            #pragma unroll
            for (int j = 0; j < 8; ++j)
                acc[j] = fmaf(v, (float)hv[j], acc[j]);
        }
    }

    #pragma unroll
    for (int j = 0; j < 8; ++j)
        acc[j] = fmaxf(acc[j] + bias[c8 + j], 0.f);

    float4 o0 = make_float4(acc[0], acc[1], acc[2], acc[3]);
    float4 o1 = make_float4(acc[4], acc[5], acc[6], acc[7]);
    *(float4*)(out + (size_t)row * OUT_F + c8)     = o0;
    *(float4*)(out + (size_t)row * OUT_F + c8 + 4) = o1;
}

extern "C" void kernel_launch(void* const* d_in, const int* in_sizes, int n_in,
                              void* d_out, int out_size, void* d_ws, size_t ws_size,
                              hipStream_t stream)
{
    const int*   row_ptr = (const int*)  d_in[1];
    const int*   col_idx = (const int*)  d_in[2];
    const float* edgeval = (const float*)d_in[3];
    const float* in_feat = (const float*)d_in[11];
    const float* W       = (const float*)d_in[12];
    const float* bias    = (const float*)d_in[13];

    const int n = in_sizes[11] / IN_F;   // 50000 nodes

    __bf16* H  = (__bf16*)d_ws;                                  // [n][128] bf16
    __bf16* Wt = (__bf16*)((char*)d_ws + (size_t)n * OUT_F * 2); // [128][256] bf16

    wprep_kernel<<<IN_F, OUT_F, 0, stream>>>(W, Wt);

    const int gemm_blocks = (n + BM - 1) / BM;
    gemm_xw_kernel<<<gemm_blocks, GEMM_THREADS, 0, stream>>>(in_feat, Wt, H, n);

    const int spmm_blocks = (n + 15) / 16;
    spmm_bias_relu_kernel<<<spmm_blocks, 256, 0, stream>>>(
        row_ptr, col_idx, edgeval, H, bias, (float*)d_out, n);
}

// Round 5
// 54.511 us; speedup vs baseline: 2.5457x; 1.2457x over previous
//
#include <hip/hip_runtime.h>
#include <hip/hip_bf16.h>

#define IN_F 256
#define OUT_F 128
#define BM 32                 // GEMM rows per tile
#define GEMM_THREADS 512      // 8 waves: 2 (M) x 4 (N)
#define GEMM_BLOCKS 512       // persistent-ish; grid-stride over tiles

typedef __bf16 bf16x8 __attribute__((ext_vector_type(8)));
typedef float  f32x4  __attribute__((ext_vector_type(4)));
typedef int    i32x4  __attribute__((ext_vector_type(4)));

// -------- Kernel 0: Wt[n][k] = bf16(W[k][n])  (128x256 bf16, 64 KB) --------
__global__ __launch_bounds__(128)
void wprep_kernel(const float* __restrict__ W, __bf16* __restrict__ Wt)
{
    const int k = blockIdx.x;      // 0..255
    const int nn = threadIdx.x;    // 0..127
    Wt[nn * IN_F + k] = (__bf16)W[k * OUT_F + nn];
}

// -------- Kernel 1: H = bf16(X @ W) via MFMA, persistent blocks --------
__global__ __launch_bounds__(GEMM_THREADS)
void gemm_xw_kernel(const float* __restrict__ X, const __bf16* __restrict__ Wt,
                    __bf16* __restrict__ H, int n, int ntiles)
{
    __shared__ __bf16 xs[2][BM * IN_F];   // 2 x 16 KB, XOR-swizzled

    const int tid  = threadIdx.x;
    const int lane = tid & 63;
    const int wid  = tid >> 6;         // 0..7
    const int wm   = wid >> 2;         // 0..1 (16-row band)
    const int wn   = wid & 3;          // 0..3 (32-col band)

    // ---- load B fragments ONCE per block (Wt is L2-resident) ----
    // frag layout: n = lane&15, k = (lane>>4)*8 + j
    bf16x8 bfrag[8][2];
    {
        const int nbase = wn * 32 + (lane & 15);
        const int kbase = (lane >> 4) * 8;
        #pragma unroll
        for (int kk = 0; kk < 8; ++kk) {
            #pragma unroll
            for (int nf = 0; nf < 2; ++nf) {
                const __bf16* p = Wt + (size_t)(nbase + nf * 16) * IN_F + kk * 32 + kbase;
                bfrag[kk][nf] = *(const bf16x8*)p;
            }
        }
    }

    // per-thread staging coords: chunk0 -> rows 0..15, chunk1 -> rows 16..31
    const int srow = tid >> 5;           // 0..15
    const int sk   = (tid & 31) * 8;     // 0..248

    // ---- prologue: stage first tile into buf 0 ----
    int tile = blockIdx.x;
    if (tile < ntiles) {
        const int r0 = tile * BM;
        float4 a0 = make_float4(0,0,0,0), a1 = a0, b0 = a0, b1 = a0;
        const int gr0 = r0 + srow, gr1 = r0 + srow + 16;
        if (gr0 < n) {
            a0 = *(const float4*)(X + (size_t)gr0 * IN_F + sk);
            a1 = *(const float4*)(X + (size_t)gr0 * IN_F + sk + 4);
        }
        if (gr1 < n) {
            b0 = *(const float4*)(X + (size_t)gr1 * IN_F + sk);
            b1 = *(const float4*)(X + (size_t)gr1 * IN_F + sk + 4);
        }
        bf16x8 v0, v1;
        v0[0]=(__bf16)a0.x; v0[1]=(__bf16)a0.y; v0[2]=(__bf16)a0.z; v0[3]=(__bf16)a0.w;
        v0[4]=(__bf16)a1.x; v0[5]=(__bf16)a1.y; v0[6]=(__bf16)a1.z; v0[7]=(__bf16)a1.w;
        v1[0]=(__bf16)b0.x; v1[1]=(__bf16)b0.y; v1[2]=(__bf16)b0.z; v1[3]=(__bf16)b0.w;
        v1[4]=(__bf16)b1.x; v1[5]=(__bf16)b1.y; v1[6]=(__bf16)b1.z; v1[7]=(__bf16)b1.w;
        *(bf16x8*)&xs[0][(srow * IN_F + sk) ^ ((srow & 7) << 3)] = v0;
        *(bf16x8*)&xs[0][((srow + 16) * IN_F + sk) ^ (((srow + 16) & 7) << 3)] = v1;
    }
    __syncthreads();

    int cur = 0;
    for (; tile < ntiles; tile += gridDim.x) {
        const int nxt = tile + (int)gridDim.x;
        const bool has_next = nxt < ntiles;

        // ---- issue next tile's global loads early (hide under MFMA) ----
        float4 a0 = make_float4(0,0,0,0), a1 = a0, b0 = a0, b1 = a0;
        if (has_next) {
            const int r0 = nxt * BM;
            const int gr0 = r0 + srow, gr1 = r0 + srow + 16;
            if (gr0 < n) {
                a0 = *(const float4*)(X + (size_t)gr0 * IN_F + sk);
                a1 = *(const float4*)(X + (size_t)gr0 * IN_F + sk + 4);
            }
            if (gr1 < n) {
                b0 = *(const float4*)(X + (size_t)gr1 * IN_F + sk);
                b1 = *(const float4*)(X + (size_t)gr1 * IN_F + sk + 4);
            }
        }

        // ---- MFMA on current buffer ----
        f32x4 acc0 = (f32x4)0.f, acc1 = (f32x4)0.f;
        {
            const int arow  = wm * 16 + (lane & 15);
            const int akoff = (lane >> 4) * 8;
            #pragma unroll
            for (int kk = 0; kk < 8; ++kk) {
                const int sidx = (arow * IN_F + kk * 32 + akoff) ^ ((arow & 7) << 3);
                const bf16x8 a = *(const bf16x8*)&xs[cur][sidx];
                acc0 = __builtin_amdgcn_mfma_f32_16x16x32_bf16(a, bfrag[kk][0], acc0, 0, 0, 0);
                acc1 = __builtin_amdgcn_mfma_f32_16x16x32_bf16(a, bfrag[kk][1], acc1, 0, 0, 0);
            }
        }

        // ---- store H tile (C/D layout: col=lane&15, row=(lane>>4)*4+j) ----
        {
            const int crow0 = tile * BM + wm * 16 + (lane >> 4) * 4;
            const int ccol0 = wn * 32 + (lane & 15);
            #pragma unroll
            for (int j = 0; j < 4; ++j) {
                const int row = crow0 + j;
                if (row < n) {
                    H[(size_t)row * OUT_F + ccol0]      = (__bf16)acc0[j];
                    H[(size_t)row * OUT_F + ccol0 + 16] = (__bf16)acc1[j];
                }
            }
        }

        // ---- convert + write next tile into the other buffer ----
        if (has_next) {
            bf16x8 v0, v1;
            v0[0]=(__bf16)a0.x; v0[1]=(__bf16)a0.y; v0[2]=(__bf16)a0.z; v0[3]=(__bf16)a0.w;
            v0[4]=(__bf16)a1.x; v0[5]=(__bf16)a1.y; v0[6]=(__bf16)a1.z; v0[7]=(__bf16)a1.w;
            v1[0]=(__bf16)b0.x; v1[1]=(__bf16)b0.y; v1[2]=(__bf16)b0.z; v1[3]=(__bf16)b0.w;
            v1[4]=(__bf16)b1.x; v1[5]=(__bf16)b1.y; v1[6]=(__bf16)b1.z; v1[7]=(__bf16)b1.w;
            const int nb = cur ^ 1;
            *(bf16x8*)&xs[nb][(srow * IN_F + sk) ^ ((srow & 7) << 3)] = v0;
            *(bf16x8*)&xs[nb][((srow + 16) * IN_F + sk) ^ (((srow + 16) & 7) << 3)] = v1;
        }
        __syncthreads();
        cur ^= 1;
    }
}

// -------- Kernel 2: out = relu(A @ H + bias)  (CSR, H bf16, acc f32) --------
__global__ __launch_bounds__(256)
void spmm_bias_relu_kernel(const int* __restrict__ row_ptr,
                           const int* __restrict__ col_idx,
                           const float* __restrict__ val,
                           const __bf16* __restrict__ H,
                           const float* __restrict__ bias,
                           float* __restrict__ out, int n)
{
    const int row = blockIdx.x * 16 + (threadIdx.x >> 4);
    const int c8  = (threadIdx.x & 15) * 8;
    if (row >= n) return;

    const int s = row_ptr[row];
    const int e = row_ptr[row + 1];

    float acc[8];
    #pragma unroll
    for (int j = 0; j < 8; ++j) acc[j] = 0.f;

    if (e - s == 16 && (s & 3) == 0) {
        // fast path: 16 edges; nontemporal metadata (read-once), cached H gathers
        i32x4 ci[4];
        f32x4 vi[4];
        #pragma unroll
        for (int i = 0; i < 4; ++i) {
            ci[i] = __builtin_nontemporal_load((const i32x4*)(col_idx + s) + i);
            vi[i] = __builtin_nontemporal_load((const f32x4*)(val + s) + i);
        }
        int   cols[16];
        float vals[16];
        #pragma unroll
        for (int i = 0; i < 4; ++i) {
            #pragma unroll
            for (int j = 0; j < 4; ++j) {
                cols[i * 4 + j] = ci[i][j];
                vals[i * 4 + j] = vi[i][j];
            }
        }
        bf16x8 hv[16];
        #pragma unroll
        for (int i = 0; i < 16; ++i)
            hv[i] = *(const bf16x8*)(H + (size_t)cols[i] * OUT_F + c8);
        #pragma unroll
        for (int i = 0; i < 16; ++i) {
            #pragma unroll
            for (int j = 0; j < 8; ++j)
                acc[j] = fmaf(vals[i], (float)hv[i][j], acc[j]);
        }
    } else {
        for (int ee = s; ee < e; ++ee) {
            const int   col = col_idx[ee];
            const float v   = val[ee];
            const bf16x8 hv = *(const bf16x8*)(H + (size_t)col * OUT_F + c8);
            #pragma unroll
            for (int j = 0; j < 8; ++j)
                acc[j] = fmaf(v, (float)hv[j], acc[j]);
        }
    }

    #pragma unroll
    for (int j = 0; j < 8; ++j)
        acc[j] = fmaxf(acc[j] + bias[c8 + j], 0.f);

    f32x4 o0 = { acc[0], acc[1], acc[2], acc[3] };
    f32x4 o1 = { acc[4], acc[5], acc[6], acc[7] };
    __builtin_nontemporal_store(o0, (f32x4*)(out + (size_t)row * OUT_F + c8));
    __builtin_nontemporal_store(o1, (f32x4*)(out + (size_t)row * OUT_F + c8 + 4));
}

extern "C" void kernel_launch(void* const* d_in, const int* in_sizes, int n_in,
                              void* d_out, int out_size, void* d_ws, size_t ws_size,
                              hipStream_t stream)
{
    const int*   row_ptr = (const int*)  d_in[1];
    const int*   col_idx = (const int*)  d_in[2];
    const float* edgeval = (const float*)d_in[3];
    const float* in_feat = (const float*)d_in[11];
    const float* W       = (const float*)d_in[12];
    const float* bias    = (const float*)d_in[13];

    const int n = in_sizes[11] / IN_F;   // 50000 nodes

    __bf16* H  = (__bf16*)d_ws;                                  // [n][128] bf16
    __bf16* Wt = (__bf16*)((char*)d_ws + (size_t)n * OUT_F * 2); // [128][256] bf16

    wprep_kernel<<<IN_F, OUT_F, 0, stream>>>(W, Wt);

    const int ntiles = (n + BM - 1) / BM;
    const int gemm_blocks = ntiles < GEMM_BLOCKS ? ntiles : GEMM_BLOCKS;
    gemm_xw_kernel<<<gemm_blocks, GEMM_THREADS, 0, stream>>>(in_feat, Wt, H, n, ntiles);

    const int spmm_blocks = (n + 15) / 16;
    spmm_bias_relu_kernel<<<spmm_blocks, 256, 0, stream>>>(
        row_ptr, col_idx, edgeval, H, bias, (float*)d_out, n);
}